// Round 2
// baseline (6034.069 us; speedup 1.0000x reference)
//
#include <hip/hip_runtime.h>
#include <hip/hip_bf16.h>
#include <cstddef>

#define T_SEQ 2048
#define BATCH 64
#define H 128
#define EPS 1e-5f

typedef _Float16 half8_t __attribute__((ext_vector_type(8)));
typedef _Float16 half4_t __attribute__((ext_vector_type(4)));
typedef float floatx4 __attribute__((ext_vector_type(4)));

// ---------- math helpers ----------
__device__ __forceinline__ float sigmoid_f(float x) {
    // exp(-x)->inf for very negative x gives rcp(inf)=0: correct saturation
    return __builtin_amdgcn_rcpf(1.0f + __expf(-x));
}
__device__ __forceinline__ float tanh_f(float x) {
    return fmaf(2.0f, __builtin_amdgcn_rcpf(1.0f + __expf(-2.0f * x)), -1.0f);
}
__device__ __forceinline__ float mish_f(float x) {
    float sp = (x > 15.0f) ? x : log1pf(__expf(x));
    return x * tanh_f(sp);
}

// ---------- input-projection GEMM (unchanged, validated) ----------
template<int K>
__global__ __launch_bounds__(256, 2)
void proj_kernel(const float* __restrict__ A, const float* __restrict__ W,
                 const float* __restrict__ bias, float* __restrict__ C)
{
    __shared__ float As[16][128];
    __shared__ float Ws[16][128];
    const int n0 = blockIdx.x * 128;
    const int m0 = blockIdx.y * 128;
    const int tid = threadIdx.x;
    const int tx = tid & 15;
    const int ty = tid >> 4;
    float acc[8][8];
    #pragma unroll
    for (int i = 0; i < 8; ++i)
        #pragma unroll
        for (int j = 0; j < 8; ++j) acc[i][j] = 0.0f;

    for (int k0 = 0; k0 < K; k0 += 16) {
        #pragma unroll
        for (int i = 0; i < 2; ++i) {
            const int f = tid + i * 256;
            const int r = f >> 2;
            const int kq = (f & 3) << 2;
            const int m = m0 + r;
            const size_t arow = (size_t)(m & 63) * T_SEQ + (m >> 6); // b*T+t
            const float4 av = *reinterpret_cast<const float4*>(&A[arow * K + k0 + kq]);
            As[kq + 0][r] = av.x; As[kq + 1][r] = av.y;
            As[kq + 2][r] = av.z; As[kq + 3][r] = av.w;
            const float4 wv = *reinterpret_cast<const float4*>(&W[(size_t)(n0 + r) * K + k0 + kq]);
            Ws[kq + 0][r] = wv.x; Ws[kq + 1][r] = wv.y;
            Ws[kq + 2][r] = wv.z; Ws[kq + 3][r] = wv.w;
        }
        __syncthreads();
        #pragma unroll
        for (int kk = 0; kk < 16; ++kk) {
            float a[8], b[8];
            *reinterpret_cast<float4*>(&a[0]) = *reinterpret_cast<const float4*>(&As[kk][ty * 8]);
            *reinterpret_cast<float4*>(&a[4]) = *reinterpret_cast<const float4*>(&As[kk][ty * 8 + 4]);
            *reinterpret_cast<float4*>(&b[0]) = *reinterpret_cast<const float4*>(&Ws[kk][tx * 8]);
            *reinterpret_cast<float4*>(&b[4]) = *reinterpret_cast<const float4*>(&Ws[kk][tx * 8 + 4]);
            #pragma unroll
            for (int i = 0; i < 8; ++i)
                #pragma unroll
                for (int j = 0; j < 8; ++j)
                    acc[i][j] = fmaf(a[i], b[j], acc[i][j]);
        }
        __syncthreads();
    }
    float bv[8];
    #pragma unroll
    for (int j = 0; j < 8; ++j) bv[j] = bias[n0 + tx * 8 + j];
    #pragma unroll
    for (int i = 0; i < 8; ++i) {
        const int m = m0 + ty * 8 + i;
        float* crow = &C[(size_t)m * 384 + n0 + tx * 8];
        float4 o0, o1;
        o0.x = acc[i][0] + bv[0]; o0.y = acc[i][1] + bv[1];
        o0.z = acc[i][2] + bv[2]; o0.w = acc[i][3] + bv[3];
        o1.x = acc[i][4] + bv[4]; o1.y = acc[i][5] + bv[5];
        o1.z = acc[i][6] + bv[6]; o1.w = acc[i][7] + bv[7];
        *reinterpret_cast<float4*>(&crow[0]) = o0;
        *reinterpret_cast<float4*>(&crow[4]) = o1;
    }
}

// ---------- MFMA GRU scan ----------
// Block = (batch-group of 16, direction). 512 threads = 8 waves.
// Wave w owns M-tile trio {w (r-rows), 8+w (z-rows), 16+w (n-rows)} of the
// [384 x 128] Whh, as fp16 A-fragments resident in VGPRs.
// Per step: gates[384x16] = Whh . h[128x16] via mfma_f32_16x16x32_f16.
// D layout: col(batch)=lane&15, row=(lane>>4)*4+reg -- identical for the
// trio, so r/z/n pair in-register and h_prev stays in registers (fp32).
// h is redistributed per step through an XOR-swizzled double-buffered LDS
// buffer as fp16 B-fragments (one barrier per step).
// k-permutation consistency: A and B fragments both use k=(lane>>4)*8+j.
__device__ __forceinline__ int hoff(int n, int k) {
    return (n * 256 + k * 2) ^ ((n & 7) << 4);
}

__global__ __launch_bounds__(512, 1)
void gru_scan_mfma(const float* __restrict__ xpA, const float* __restrict__ xpB,
                   const float* __restrict__ WA, const float* __restrict__ WB,
                   const float* __restrict__ bA, const float* __restrict__ bB,
                   int revA, int revB,
                   float* __restrict__ seqout,   // x1 [B][T][256] or nullptr
                   float* __restrict__ hfin)     // [B][H] or nullptr
{
    const int dir = blockIdx.y;
    const float* __restrict__ xp  = dir ? xpB : xpA;
    const float* __restrict__ Whh = dir ? WB : WA;
    const float* __restrict__ bhh = dir ? bB : bA;
    const int rev = dir ? revB : revA;
    const int g0 = blockIdx.x * 16;

    const int tid = threadIdx.x;
    const int w = tid >> 6;        // wave 0..7
    const int l = tid & 63;
    const int n = l & 15;          // batch slot (B-frag col, D col, A row slot)
    const int q = l >> 4;          // lane quarter (k-group / D row group)

    __shared__ __align__(16) unsigned char hlds[2][4096];

    // zero h buffer 0 (h0 = 0)
    for (int i = tid; i < 1024; i += 512)
        reinterpret_cast<unsigned*>(hlds[0])[i] = 0u;

    // Whh fragments -> fp16, resident
    half8_t wf[3][4];
    #pragma unroll
    for (int mi = 0; mi < 3; ++mi) {
        const int tile = mi * 8 + w;
        const float* wr = &Whh[(size_t)(tile * 16 + n) * 128 + q * 8];
        #pragma unroll
        for (int kt = 0; kt < 4; ++kt) {
            floatx4 w0 = *reinterpret_cast<const floatx4*>(wr + kt * 32);
            floatx4 w1 = *reinterpret_cast<const floatx4*>(wr + kt * 32 + 4);
            half8_t hf;
            hf[0] = (_Float16)w0[0]; hf[1] = (_Float16)w0[1];
            hf[2] = (_Float16)w0[2]; hf[3] = (_Float16)w0[3];
            hf[4] = (_Float16)w1[0]; hf[5] = (_Float16)w1[1];
            hf[6] = (_Float16)w1[2]; hf[7] = (_Float16)w1[3];
            wf[mi][kt] = hf;
        }
    }

    const int rowq = w * 16 + q * 4;          // D-layout row base (h-dim / gate sub-row)
    const int batch = g0 + n;

    const floatx4 bR = *reinterpret_cast<const floatx4*>(&bhh[rowq]);
    const floatx4 bZ = *reinterpret_cast<const floatx4*>(&bhh[128 + rowq]);
    const floatx4 bN = *reinterpret_cast<const floatx4*>(&bhh[256 + rowq]);

    floatx4 hp = {0.f, 0.f, 0.f, 0.f};        // h_prev rows rowq..rowq+3, col batch

    int t = rev ? (T_SEQ - 1) : 0;
    const int tstep = rev ? -1 : 1;

    const float* xrow = &xp[((size_t)t * BATCH + batch) * 384 + rowq];
    floatx4 xR = *reinterpret_cast<const floatx4*>(xrow);
    floatx4 xZ = *reinterpret_cast<const floatx4*>(xrow + 128);
    floatx4 xN = *reinterpret_cast<const floatx4*>(xrow + 256);

    __syncthreads();
    int p = 0;

    for (int s = 0; s < T_SEQ; ++s) {
        // B-fragments of current h
        half8_t bf0 = *reinterpret_cast<const half8_t*>(&hlds[p][hoff(n, 0 * 32 + q * 8)]);
        half8_t bf1 = *reinterpret_cast<const half8_t*>(&hlds[p][hoff(n, 1 * 32 + q * 8)]);
        half8_t bf2 = *reinterpret_cast<const half8_t*>(&hlds[p][hoff(n, 2 * 32 + q * 8)]);
        half8_t bf3 = *reinterpret_cast<const half8_t*>(&hlds[p][hoff(n, 3 * 32 + q * 8)]);

        // prefetch next step's xp during compute
        floatx4 xRn = {0.f,0.f,0.f,0.f}, xZn = {0.f,0.f,0.f,0.f}, xNn = {0.f,0.f,0.f,0.f};
        if (s + 1 < T_SEQ) {
            const float* xnrow = &xp[((size_t)(t + tstep) * BATCH + batch) * 384 + rowq];
            xRn = *reinterpret_cast<const floatx4*>(xnrow);
            xZn = *reinterpret_cast<const floatx4*>(xnrow + 128);
            xNn = *reinterpret_cast<const floatx4*>(xnrow + 256);
        }

        floatx4 a0 = {0.f,0.f,0.f,0.f}, a1 = {0.f,0.f,0.f,0.f}, a2 = {0.f,0.f,0.f,0.f};
        a0 = __builtin_amdgcn_mfma_f32_16x16x32_f16(wf[0][0], bf0, a0, 0, 0, 0);
        a1 = __builtin_amdgcn_mfma_f32_16x16x32_f16(wf[1][0], bf0, a1, 0, 0, 0);
        a2 = __builtin_amdgcn_mfma_f32_16x16x32_f16(wf[2][0], bf0, a2, 0, 0, 0);
        a0 = __builtin_amdgcn_mfma_f32_16x16x32_f16(wf[0][1], bf1, a0, 0, 0, 0);
        a1 = __builtin_amdgcn_mfma_f32_16x16x32_f16(wf[1][1], bf1, a1, 0, 0, 0);
        a2 = __builtin_amdgcn_mfma_f32_16x16x32_f16(wf[2][1], bf1, a2, 0, 0, 0);
        a0 = __builtin_amdgcn_mfma_f32_16x16x32_f16(wf[0][2], bf2, a0, 0, 0, 0);
        a1 = __builtin_amdgcn_mfma_f32_16x16x32_f16(wf[1][2], bf2, a1, 0, 0, 0);
        a2 = __builtin_amdgcn_mfma_f32_16x16x32_f16(wf[2][2], bf2, a2, 0, 0, 0);
        a0 = __builtin_amdgcn_mfma_f32_16x16x32_f16(wf[0][3], bf3, a0, 0, 0, 0);
        a1 = __builtin_amdgcn_mfma_f32_16x16x32_f16(wf[1][3], bf3, a1, 0, 0, 0);
        a2 = __builtin_amdgcn_mfma_f32_16x16x32_f16(wf[2][3], bf3, a2, 0, 0, 0);

        // gates (fp32): r = sig(Dr+bhr+xr), z = sig(Dz+bhz+xz),
        // nn = tanh(xn + r*(Dn+bhn)), h = z*(hp-nn)+nn
        floatx4 hnew;
        half4_t hh;
        #pragma unroll
        for (int rr = 0; rr < 4; ++rr) {
            const float rg = sigmoid_f(a0[rr] + bR[rr] + xR[rr]);
            const float zg = sigmoid_f(a1[rr] + bZ[rr] + xZ[rr]);
            const float ng = tanh_f(xN[rr] + rg * (a2[rr] + bN[rr]));
            const float hv = fmaf(zg, hp[rr] - ng, ng);
            hnew[rr] = hv;
            hh[rr] = (_Float16)hv;
        }
        hp = hnew;

        // publish h_new for next step (other buffer)
        *reinterpret_cast<half4_t*>(&hlds[p ^ 1][hoff(n, rowq)]) = hh;

        if (seqout)
            *reinterpret_cast<floatx4*>(
                &seqout[((size_t)batch * T_SEQ + t) * 256 + dir * 128 + rowq]) = hnew;

        __syncthreads();
        p ^= 1;
        t += tstep;
        xR = xRn; xZ = xZn; xN = xNn;
    }

    if (hfin)
        *reinterpret_cast<floatx4*>(&hfin[(size_t)batch * 128 + rowq]) = hp;
}

// ---------- decoder ----------
__device__ __forceinline__ float block_sum128(float v, float* red) {
    #pragma unroll
    for (int o = 32; o > 0; o >>= 1) v += __shfl_down(v, o);
    const int w = threadIdx.x >> 6;
    if ((threadIdx.x & 63) == 0) red[w] = v;
    __syncthreads();
    const float s = red[0] + red[1];
    __syncthreads();
    return s;
}

__global__ __launch_bounds__(128, 1)
void decoder_kernel(const float* __restrict__ hb,
                    const float* __restrict__ g1, const float* __restrict__ be1,
                    const float* __restrict__ W1, const float* __restrict__ b1,
                    const float* __restrict__ g2, const float* __restrict__ be2,
                    const float* __restrict__ W2, const float* __restrict__ b2,
                    float* __restrict__ out)
{
    const int b = blockIdx.x;
    const int j = threadIdx.x;
    __shared__ float buf[H];
    __shared__ float red[2];

    const float m = mish_f(hb[(size_t)b * H + j]);
    const float mean = block_sum128(m, red) * (1.0f / H);
    const float d = m - mean;
    const float var = block_sum128(d * d, red) * (1.0f / H);
    const float y = d * rsqrtf(var + EPS) * g1[j] + be1[j];
    buf[j] = y;
    __syncthreads();

    float acc = b1[j];
    #pragma unroll
    for (int k = 0; k < H; k += 4) {
        const float4 wv = *reinterpret_cast<const float4*>(&W1[(size_t)j * H + k]);
        const float4 yv = *reinterpret_cast<const float4*>(&buf[k]);
        acc += wv.x * yv.x + wv.y * yv.y + wv.z * yv.z + wv.w * yv.w;
    }
    const float m2 = mish_f(acc);
    const float mean2 = block_sum128(m2, red) * (1.0f / H);
    const float d2 = m2 - mean2;
    const float var2 = block_sum128(d2 * d2, red) * (1.0f / H);
    const float y2 = d2 * rsqrtf(var2 + EPS) * g2[j] + be2[j];

    const float p = W2[j] * y2;
    const float s = block_sum128(p, red);
    if (j == 0) out[b] = s + b2[0];
}

// ---------- launch ----------
extern "C" void kernel_launch(void* const* d_in, const int* in_sizes, int n_in,
                              void* d_out, int out_size, void* d_ws, size_t ws_size,
                              hipStream_t stream)
{
    (void)in_sizes; (void)n_in; (void)out_size; (void)ws_size;
    const float* x     = (const float*)d_in[0];
    const float* Wih0f = (const float*)d_in[1];
    const float* Whh0f = (const float*)d_in[2];
    const float* bih0f = (const float*)d_in[3];
    const float* bhh0f = (const float*)d_in[4];
    const float* Wih0b = (const float*)d_in[5];
    const float* Whh0b = (const float*)d_in[6];
    const float* bih0b = (const float*)d_in[7];
    const float* bhh0b = (const float*)d_in[8];
    // d_in[9..12] = layer-1 forward params: unused (hf discarded by reference)
    const float* Wih1b = (const float*)d_in[13];
    const float* Whh1b = (const float*)d_in[14];
    const float* bih1b = (const float*)d_in[15];
    const float* bhh1b = (const float*)d_in[16];
    const float* g1  = (const float*)d_in[17];
    const float* be1 = (const float*)d_in[18];
    const float* W1  = (const float*)d_in[19];
    const float* b1  = (const float*)d_in[20];
    const float* g2  = (const float*)d_in[21];
    const float* be2 = (const float*)d_in[22];
    const float* W2  = (const float*)d_in[23];
    const float* b2  = (const float*)d_in[24];
    float* out = (float*)d_out;

    float* ws = (float*)d_ws;
    const size_t XP_ELEMS = (size_t)T_SEQ * BATCH * 384;
    const size_t X1_ELEMS = (size_t)BATCH * T_SEQ * 256;
    float* xp0f = ws;
    float* xp0b = xp0f + XP_ELEMS;
    float* x1   = xp0b + XP_ELEMS;
    float* hbuf = x1 + X1_ELEMS;
    float* xp1b = xp0f;   // xp0f dead after layer-0 scan

    const dim3 pgrid(3, 1024);
    proj_kernel<512><<<pgrid, 256, 0, stream>>>(x, Wih0f, bih0f, xp0f);
    proj_kernel<512><<<pgrid, 256, 0, stream>>>(x, Wih0b, bih0b, xp0b);
    gru_scan_mfma<<<dim3(4, 2), 512, 0, stream>>>(xp0f, xp0b, Whh0f, Whh0b, bhh0f, bhh0b,
                                                  0, 1, x1, nullptr);
    proj_kernel<256><<<pgrid, 256, 0, stream>>>(x1, Wih1b, bih1b, xp1b);
    gru_scan_mfma<<<dim3(4, 1), 512, 0, stream>>>(xp1b, xp1b, Whh1b, Whh1b, bhh1b, bhh1b,
                                                  1, 1, nullptr, hbuf);
    decoder_kernel<<<64, 128, 0, stream>>>(hbuf, g1, be1, W1, b1, g2, be2, W2, b2, out);
}